// Round 9
// baseline (576.009 us; speedup 1.0000x reference)
//
#include <hip/hip_runtime.h>

typedef unsigned int uint_t;
typedef unsigned short ushort_t;
typedef unsigned long long ull_t;
typedef uint_t nvec4 __attribute__((ext_vector_type(4)));  // native vec for NT builtin

#define SLOTS 64   // per-row index capacity; Binomial(8192,~1e-3) max ~28

__device__ __forceinline__ float bcast(float v, int k) {
    union { float f; int i; } x; x.f = v;
    int r = __builtin_amdgcn_readlane(x.i, k);
    union { int i; float f; } y2; y2.i = r;
    return y2.f;
}

// ---------------------------------------------------------------------------
// Kernel A: fused stream + gather, block-per-4-rows, 4 KB sequential front.
// Evidence trail: per-wave 1 KB-front private 32 KB windows cap at 3.2 TB/s
// cached (R4-R6) / 3.8 TB/s NT (R8); the 6.3 TB/s memcpy ceiling comes from a
// device-wide linear sweep. So: each block (4 waves) owns 4 CONSECUTIVE rows
// (128 KB contiguous); wave w reads 1 KB chunks w, w+4, w+8... so the block
// sweeps its window with a contiguous 4 KB front (4x run length, 1/4 the
// window count of R8). NT loads keep the once-read stream out of the caches.
// Nonzero column indices are ballot-compacted into 4 per-row LDS slices via
// LDS-atomic reservation (~8 nonzero chunks/row -> negligible contention).
// Phase 2: wave w alone gathers y[j,:] for row w (L2-hot) -> lg_y/pd_y;
// pm blocks spill their 4 slices for the post-BN scatter.
// ---------------------------------------------------------------------------
__global__ __launch_bounds__(256) void stream_gather_kernel(
    const float* __restrict__ lg, const float* __restrict__ pd,
    const float* __restrict__ pm, const float* __restrict__ y,
    float* __restrict__ lg_y, float* __restrict__ pd_y,
    ushort_t* __restrict__ pm_keys, uint_t* __restrict__ pm_counts)
{
    __shared__ ushort_t sSlice[4][SLOTS];
    __shared__ uint_t sCnt[4];
    const int lane = threadIdx.x & 63;
    const int wv = threadIdx.x >> 6;
    const int bid = blockIdx.x;            // 4096 blocks
    const float* A;
    int row0, mat;                         // mat: 0=lg 1=pd 2=pm
    if (bid < 2048)      { mat = 0; row0 = bid * 4;          A = lg; }
    else if (bid < 3072) { mat = 1; row0 = (bid - 2048) * 4; A = pd; }
    else                 { mat = 2; row0 = (bid - 3072) * 4; A = pm; }

    if (threadIdx.x < 4) sCnt[threadIdx.x] = 0;
    __syncthreads();

    // 4 rows x 32 KB contiguous = 128 chunks of 1 KB; wave w owns chunks
    // g = w + 4*i  (i = 0..31).
    const nvec4* ap = (const nvec4*)(A + (size_t)row0 * 8192);
    const ull_t lt = (1ull << lane) - 1ull;

    nvec4 buf[8];
    #pragma unroll
    for (int i = 0; i < 8; ++i)
        buf[i] = __builtin_nontemporal_load(ap + (size_t)(wv + 4 * i) * 64 + lane);

    #pragma unroll
    for (int pp = 0; pp < 32; pp += 8) {
        #pragma unroll
        for (int i = 0; i < 8; ++i) {
            nvec4 c = buf[i];
            if (pp + 8 + i < 32)
                buf[i] = __builtin_nontemporal_load(
                    ap + (size_t)(wv + 4 * (pp + 8 + i)) * 64 + lane);
            const int g = wv + 4 * (pp + i);       // chunk 0..127 in window
            uint_t a0 = c.x, a1 = c.y, a2 = c.z, a3 = c.w;
            ull_t m = __ballot((a0 | a1 | a2 | a3) != 0u);
            if (m) {                               // ~2 of 8 chunks nonzero
                ull_t m0 = __ballot(a0 != 0u);
                ull_t m1 = __ballot(a1 != 0u);
                ull_t m2 = __ballot(a2 != 0u);
                ull_t m3 = __ballot(a3 != 0u);
                uint_t c0 = (uint_t)__popcll(m0), c1 = (uint_t)__popcll(m1);
                uint_t c2 = (uint_t)__popcll(m2), c3 = (uint_t)__popcll(m3);
                uint_t total = c0 + c1 + c2 + c3;
                const int q = g >> 5;              // row within quad
                uint_t base = 0;
                if (lane == 0) base = atomicAdd(&sCnt[q], total);
                base = (uint_t)__shfl((int)base, 0);
                uint_t o0 = base + (uint_t)__popcll(m0 & lt);
                uint_t o1 = base + c0 + (uint_t)__popcll(m1 & lt);
                uint_t o2 = base + c0 + c1 + (uint_t)__popcll(m2 & lt);
                uint_t o3 = base + c0 + c1 + c2 + (uint_t)__popcll(m3 & lt);
                int jb = (g & 31) * 256 + lane * 4;
                ushort_t* sl = sSlice[q];
                if (a0 && o0 < SLOTS) sl[o0] = (ushort_t)(jb + 0);
                if (a1 && o1 < SLOTS) sl[o1] = (ushort_t)(jb + 1);
                if (a2 && o2 < SLOTS) sl[o2] = (ushort_t)(jb + 2);
                if (a3 && o3 < SLOTS) sl[o3] = (ushort_t)(jb + 3);
            }
        }
    }
    __syncthreads();

    // Phase 2: wave wv handles row row0+wv of the quad.
    const int row = row0 + wv;
    uint_t cnt = sCnt[wv]; if (cnt > SLOTS) cnt = SLOTS;
    const ushort_t* sl = sSlice[wv];

    if (mat == 2) {                        // pm: spill slice for scatter
        if (lane == 0) pm_counts[row] = cnt;
        if (lane < (int)cnt) pm_keys[(size_t)row * SLOTS + lane] = sl[lane];
        return;
    }
    float a0 = 0.f, a1 = 0.f, a2 = 0.f, a3 = 0.f;
    uint_t i = 0;
    for (; i + 4 <= cnt; i += 4) {
        int j0 = sl[i + 0], j1 = sl[i + 1];
        int j2 = sl[i + 2], j3 = sl[i + 3];
        a0 += y[(size_t)j0 * 64 + lane];
        a1 += y[(size_t)j1 * 64 + lane];
        a2 += y[(size_t)j2 * 64 + lane];
        a3 += y[(size_t)j3 * 64 + lane];
    }
    for (; i < cnt; ++i) a0 += y[(size_t)sl[i] * 64 + lane];
    float acc = (a0 + a1) + (a2 + a3);
    if (mat == 0) lg_y[(size_t)row * 64 + lane] = acc;
    else          pd_y[(size_t)row * 64 + lane] = acc;
}

// ---------------------------------------------------------------------------
// Kernel B: x_raw = concat(pd_y@Wt.T + bt, relu(pd_y@Wr.T + br)), BN-x stats.
// ---------------------------------------------------------------------------
__global__ __launch_bounds__(256) void xlin_kernel(
    const float* __restrict__ pd_y,
    const float* __restrict__ wt, const float* __restrict__ bt,
    const float* __restrict__ wr, const float* __restrict__ br,
    float* __restrict__ x_raw, float* __restrict__ stats_x)
{
    __shared__ float red[2][4][64];
    const int wave = threadIdx.x >> 6, lane = threadIdx.x & 63;
    const float* wsrc = (lane < 32) ? (wt + lane * 64) : (wr + (lane - 32) * 64);
    float wreg[64];
    const float4* wp = (const float4*)wsrc;
    #pragma unroll
    for (int q = 0; q < 16; ++q) {
        float4 t = wp[q];
        wreg[q * 4 + 0] = t.x; wreg[q * 4 + 1] = t.y;
        wreg[q * 4 + 2] = t.z; wreg[q * 4 + 3] = t.w;
    }
    float bias = (lane < 32) ? bt[lane] : br[lane - 32];
    float s1 = 0.f, s2 = 0.f;
    const int row0 = (blockIdx.x * 4 + wave) * 8;
    for (int r = 0; r < 8; ++r) {
        int row = row0 + r;
        float xv = pd_y[(size_t)row * 64 + lane];
        float acc = bias;
        #pragma unroll
        for (int k = 0; k < 64; ++k) acc = fmaf(bcast(xv, k), wreg[k], acc);
        if (lane >= 32) acc = fmaxf(acc, 0.f);
        x_raw[(size_t)row * 64 + lane] = acc;
        s1 += acc; s2 += acc * acc;
    }
    red[0][wave][lane] = s1; red[1][wave][lane] = s2;
    __syncthreads();
    if (wave == 0) {
        float a = 0.f, b = 0.f;
        #pragma unroll
        for (int w = 0; w < 4; ++w) { a += red[0][w][lane]; b += red[1][w][lane]; }
        atomicAdd(&stats_x[lane], a);
        atomicAdd(&stats_x[64 + lane], b);
    }
}

// ---------------------------------------------------------------------------
// Kernel C: pm scatter with BN-x applied per source row (pm values are 1.0):
//   for each nz (n,e) of pm: pm_x[e,:] += BN(x_raw[n,:])
// ---------------------------------------------------------------------------
__global__ __launch_bounds__(256) void scatter_kernel(
    const ushort_t* __restrict__ pm_keys, const uint_t* __restrict__ pm_counts,
    const float* __restrict__ x_raw, const float* __restrict__ stats_x,
    const float* __restrict__ bnxw, const float* __restrict__ bnxb,
    float* __restrict__ pm_x)
{
    const int lane = threadIdx.x & 63;
    const int row = blockIdx.x * 4 + (threadIdx.x >> 6);   // 4096 pm rows
    float mean = stats_x[lane] * (1.f / 4096.f);
    float var  = fmaxf(stats_x[64 + lane] * (1.f / 4096.f) - mean * mean, 0.f);
    float rstd = rsqrtf(var + 1e-5f);
    float scale = rstd * bnxw[lane];
    float shift = bnxb[lane] - mean * scale;
    const ushort_t* slice = pm_keys + (size_t)row * SLOTS;
    uint_t cnt = pm_counts[row];
    float xb = fmaf(x_raw[(size_t)row * 64 + lane], scale, shift);
    for (uint_t i = 0; i < cnt; ++i) {
        int e = slice[i];
        atomicAdd(&pm_x[(size_t)e * 64 + lane], xb);
    }
}

// ---------------------------------------------------------------------------
// Kernel D: yraw = concat(lg_y@Wa.T+ba+bx + pm_x@Wx.T,
//                         relu(lg_y@War.T+bar+bxr + pm_x@Wxr.T)), BN-y stats.
// ---------------------------------------------------------------------------
__global__ __launch_bounds__(256) void ylin_kernel(
    const float* __restrict__ lg_y, const float* __restrict__ pm_x,
    const float* __restrict__ wa, const float* __restrict__ ba,
    const float* __restrict__ wx, const float* __restrict__ bx,
    const float* __restrict__ war, const float* __restrict__ bar,
    const float* __restrict__ wxr, const float* __restrict__ bxr,
    float* __restrict__ yraw, float* __restrict__ stats_y)
{
    __shared__ float red[2][4][64];
    const int wave = threadIdx.x >> 6, lane = threadIdx.x & 63;
    const float* s1p = (lane < 32) ? (wa + lane * 64) : (war + (lane - 32) * 64);
    const float* s2p = (lane < 32) ? (wx + lane * 64) : (wxr + (lane - 32) * 64);
    float w1[64], w2[64];
    {
        const float4* p1 = (const float4*)s1p;
        const float4* p2 = (const float4*)s2p;
        #pragma unroll
        for (int q = 0; q < 16; ++q) {
            float4 t1 = p1[q], t2 = p2[q];
            w1[q * 4 + 0] = t1.x; w1[q * 4 + 1] = t1.y;
            w1[q * 4 + 2] = t1.z; w1[q * 4 + 3] = t1.w;
            w2[q * 4 + 0] = t2.x; w2[q * 4 + 1] = t2.y;
            w2[q * 4 + 2] = t2.z; w2[q * 4 + 3] = t2.w;
        }
    }
    float bias = (lane < 32) ? (ba[lane] + bx[lane])
                             : (bar[lane - 32] + bxr[lane - 32]);
    float s1 = 0.f, s2 = 0.f;
    const int row0 = (blockIdx.x * 4 + wave) * 8;
    for (int r = 0; r < 8; ++r) {
        int row = row0 + r;
        float lv = lg_y[(size_t)row * 64 + lane];
        float pv = pm_x[(size_t)row * 64 + lane];
        float acc = bias;
        #pragma unroll
        for (int k = 0; k < 64; ++k) {
            acc = fmaf(bcast(lv, k), w1[k], acc);
            acc = fmaf(bcast(pv, k), w2[k], acc);
        }
        if (lane >= 32) acc = fmaxf(acc, 0.f);
        yraw[(size_t)row * 64 + lane] = acc;
        s1 += acc; s2 += acc * acc;
    }
    red[0][wave][lane] = s1; red[1][wave][lane] = s2;
    __syncthreads();
    if (wave == 0) {
        float a = 0.f, b = 0.f;
        #pragma unroll
        for (int w = 0; w < 4; ++w) { a += red[0][w][lane]; b += red[1][w][lane]; }
        atomicAdd(&stats_y[lane], a);
        atomicAdd(&stats_y[64 + lane], b);
    }
}

// ---------------------------------------------------------------------------
// Kernel E: final BN over yraw (in d_out), in place. 524288 elements fp32.
// ---------------------------------------------------------------------------
__global__ __launch_bounds__(256) void bny_kernel(
    float* __restrict__ yraw, const float* __restrict__ stats_y,
    const float* __restrict__ bnyw, const float* __restrict__ bnyb)
{
    int idx = blockIdx.x * 256 + threadIdx.x;
    int c = idx & 63;
    float mean = stats_y[c] * (1.f / 8192.f);
    float var  = fmaxf(stats_y[64 + c] * (1.f / 8192.f) - mean * mean, 0.f);
    float rstd = rsqrtf(var + 1e-5f);
    yraw[idx] = (yraw[idx] - mean) * rstd * bnyw[c] + bnyb[c];
}

extern "C" void kernel_launch(void* const* d_in, const int* in_sizes, int n_in,
                              void* d_out, int out_size, void* d_ws, size_t ws_size,
                              hipStream_t stream)
{
    const float* y     = (const float*)d_in[0];
    // d_in[1]=deg_g, d_in[2]=g_a1: unused in forward
    const float* lg_a1 = (const float*)d_in[3];
    const float* pm    = (const float*)d_in[4];
    const float* pd    = (const float*)d_in[5];
    const float* th_w  = (const float*)d_in[6];
    const float* th_b  = (const float*)d_in[7];
    const float* thr_w = (const float*)d_in[8];
    const float* thr_b = (const float*)d_in[9];
    const float* ga_w  = (const float*)d_in[10];
    const float* ga_b  = (const float*)d_in[11];
    const float* gx_w  = (const float*)d_in[12];
    const float* gx_b  = (const float*)d_in[13];
    const float* gar_w = (const float*)d_in[14];
    const float* gar_b = (const float*)d_in[15];
    const float* gxr_w = (const float*)d_in[16];
    const float* gxr_b = (const float*)d_in[17];
    const float* bnx_w = (const float*)d_in[18];
    const float* bnx_b = (const float*)d_in[19];
    const float* bny_w = (const float*)d_in[20];
    const float* bny_b = (const float*)d_in[21];

    char* ws = (char*)d_ws;
    float* stats_x = (float*)ws;                          // 128 f
    float* stats_y = (float*)(ws + 1024);                 // 128 f
    float* pm_x    = (float*)(ws + 2048);                 // 8192*64 f = 2 MB
    const size_t zero_bytes = 2048 + (size_t)8192 * 64 * 4;
    float* pd_y  = (float*)(ws + zero_bytes);             // 4096*64 f = 1 MB
    float* lg_y  = pd_y + (size_t)4096 * 64;              // 8192*64 f = 2 MB
    float* x_raw = lg_y + (size_t)8192 * 64;              // 4096*64 f = 1 MB
    ushort_t* pm_keys = (ushort_t*)(x_raw + (size_t)4096 * 64); // 4096*64 u16
    uint_t* pm_counts = (uint_t*)(pm_keys + (size_t)4096 * SLOTS); // 4096 u32
    float* yraw  = (float*)d_out;                         // 8192*64 f (in d_out)

    (void)hipMemsetAsync(d_ws, 0, zero_bytes, stream);   // stats + pm_x

    stream_gather_kernel<<<4096, 256, 0, stream>>>(lg_a1, pd, pm, y,
                                                   lg_y, pd_y,
                                                   pm_keys, pm_counts);
    xlin_kernel<<<128, 256, 0, stream>>>(pd_y, th_w, th_b, thr_w, thr_b,
                                         x_raw, stats_x);
    scatter_kernel<<<1024, 256, 0, stream>>>(pm_keys, pm_counts, x_raw, stats_x,
                                             bnx_w, bnx_b, pm_x);
    ylin_kernel<<<256, 256, 0, stream>>>(lg_y, pm_x, ga_w, ga_b, gx_w, gx_b,
                                         gar_w, gar_b, gxr_w, gxr_b,
                                         yraw, stats_y);
    bny_kernel<<<2048, 256, 0, stream>>>(yraw, stats_y, bny_w, bny_b);
}